// Round 2
// baseline (190.786 us; speedup 1.0000x reference)
//
#include <hip/hip_runtime.h>

#define NBATCH 128
#define NANCH  8732
#define NCLS   21

#define K1_THREADS 256
#define CHUNK 256                                  // anchors per block (1 per thread)
#define NCHUNK ((NANCH + CHUNK - 1) / CHUNK)       // 35 chunks per batch

struct BatchAcc {
    float loc;       // masked smooth-L1 sum
    float sum_all;   // sum of CE over all anchors
    float sum_pos;   // sum of CE over positive anchors
    unsigned cnt;    // positive anchor count
};

// ---------------------------------------------------------------- helpers
__device__ __forceinline__ float waveReduceF(float v) {
    #pragma unroll
    for (int o = 32; o > 0; o >>= 1) v += __shfl_down(v, o, 64);
    return v;
}
__device__ __forceinline__ unsigned waveReduceU(unsigned v) {
    #pragma unroll
    for (int o = 32; o > 0; o >>= 1) v += __shfl_down(v, o, 64);
    return v;
}

// per-anchor cross entropy from a pointer to 21 contiguous floats
__device__ __forceinline__ float con_from_row(const float* __restrict__ row, int lbl) {
    float m = row[0];
    #pragma unroll
    for (int c = 1; c < NCLS; ++c) m = fmaxf(m, row[c]);
    float s = 0.f;
    #pragma unroll
    for (int c = 0; c < NCLS; ++c) s += __expf(row[c] - m);
    return m + __logf(s) - row[lbl];
}

// ---------------------------------------------------------------- kernel 0
__global__ void init_kernel(BatchAcc* __restrict__ acc, float* __restrict__ out) {
    int i = threadIdx.x;
    if (i < NBATCH) acc[i] = BatchAcc{0.f, 0.f, 0.f, 0u};
    if (i == 0) out[0] = 0.f;
}

// ---------------------------------------------------------------- kernel 1
// One block per (batch, chunk-of-256-anchors). Coalesced float4 staging of the
// classifier rows into LDS, then one anchor per thread from LDS.
__global__ __launch_bounds__(K1_THREADS) void anchor_kernel(
    const float* __restrict__ loc_out,   // [B,A,4]
    const float* __restrict__ cls_out,   // [B,A,C]
    const float* __restrict__ loc_lab,   // [B,A,4]
    const int*   __restrict__ labels,    // [B,A]
    BatchAcc* __restrict__ acc)
{
    const int b     = blockIdx.x / NCHUNK;
    const int chunk = blockIdx.x % NCHUNK;
    const int tid   = threadIdx.x;

    const int a0  = chunk * CHUNK;                       // first anchor of chunk
    const int cnt = min(CHUNK, NANCH - a0);              // anchors in this chunk (256 or 28)
    const size_t ba0 = (size_t)b * NANCH + a0;           // multiple of 4 -> 16B aligned *21

    __shared__ float rows[CHUNK * NCLS];                 // 21504 B

    // ---- coalesced global->LDS staging of cls rows (float4, exact: cnt*21 % 4 == 0)
    const float4* __restrict__ src4 = (const float4*)(cls_out + ba0 * NCLS);
    float4* __restrict__ dst4 = (float4*)rows;
    const int nf4 = (cnt * NCLS) >> 2;                   // 1344 or 147
    for (int i = tid; i < nf4; i += K1_THREADS) dst4[i] = src4[i];

    // ---- independent coalesced loads while staging is in flight
    float loc_s = 0.f, all_s = 0.f, pos_s = 0.f;
    unsigned pcnt = 0;
    int lbl = 0;
    float4 lo4 = {0,0,0,0}, ll4 = {0,0,0,0};
    const bool active = tid < cnt;
    if (active) {
        size_t ba = ba0 + tid;
        lbl = labels[ba];
        lo4 = ((const float4*)loc_out)[ba];              // coalesced 16B/lane
        ll4 = ((const float4*)loc_lab)[ba];
    }

    __syncthreads();

    if (active) {
        float con = con_from_row(rows + tid * NCLS, lbl);
        all_s = con;
        if (lbl > 0) {
            pos_s = con;
            pcnt  = 1;
            float d0 = lo4.x - ll4.x, d1 = lo4.y - ll4.y,
                  d2 = lo4.z - ll4.z, d3 = lo4.w - ll4.w;
            float a0f = fabsf(d0), a1f = fabsf(d1), a2f = fabsf(d2), a3f = fabsf(d3);
            loc_s  = ((a0f < 1.f) ? 0.5f * d0 * d0 : (a0f - 0.5f))
                   + ((a1f < 1.f) ? 0.5f * d1 * d1 : (a1f - 0.5f))
                   + ((a2f < 1.f) ? 0.5f * d2 * d2 : (a2f - 0.5f))
                   + ((a3f < 1.f) ? 0.5f * d3 * d3 : (a3f - 0.5f));
        }
    }

    // ---- block reduction: wave shuffle then LDS
    loc_s = waveReduceF(loc_s);
    all_s = waveReduceF(all_s);
    pos_s = waveReduceF(pos_s);
    pcnt  = waveReduceU(pcnt);

    __shared__ float sLoc[4], sAll[4], sPos[4];
    __shared__ unsigned sCnt[4];
    int w = tid >> 6, lane = tid & 63;
    if (lane == 0) { sLoc[w] = loc_s; sAll[w] = all_s; sPos[w] = pos_s; sCnt[w] = pcnt; }
    __syncthreads();
    if (tid == 0) {
        float L = 0.f, S = 0.f, P = 0.f; unsigned Cc = 0;
        #pragma unroll
        for (int i = 0; i < 4; ++i) { L += sLoc[i]; S += sAll[i]; P += sPos[i]; Cc += sCnt[i]; }
        atomicAdd(&acc[b].loc, L);
        atomicAdd(&acc[b].sum_all, S);
        atomicAdd(&acc[b].sum_pos, P);
        atomicAdd(&acc[b].cnt, Cc);
    }
}

// ---------------------------------------------------------------- kernel 2
__global__ __launch_bounds__(256) void finalize_kernel(
    const float* __restrict__ cls_out,
    const int*   __restrict__ labels,
    const BatchAcc* __restrict__ acc,
    float* __restrict__ out)
{
    const int b   = blockIdx.x;
    const int tid = threadIdx.x;
    BatchAcc a = acc[b];

    long long k = (long long)3 * (long long)a.cnt;
    if (k > NANCH) k = NANCH;
    if (k == 0) k = 3;

    float con_loss;

    if (k >= NANCH) {
        // neg_mask is all-ones: con_loss = sum(con*(mask+1))
        con_loss = a.sum_all + a.sum_pos;
        if (tid == 0) {
            float denom = (a.cnt != 0u) ? (float)a.cnt : 1.f;
            atomicAdd(out, (a.loc + con_loss) / denom * (1.f / NBATCH));
        }
        return;
    }

    // ---------------- cold general path: exact top-k of con_neg ----------------
    __shared__ float    sF[256];
    __shared__ unsigned sU[256];
    __shared__ float    bcastF;

    auto count_gt = [&](float t) -> unsigned {
        unsigned c = 0;
        for (int an = tid; an < NANCH; an += 256) {
            size_t ba = (size_t)b * NANCH + an;
            int lbl = labels[ba];
            if (lbl > 0) continue;
            float con = con_from_row(cls_out + ba * NCLS, lbl);
            if (con > t) c++;
        }
        sU[tid] = c; __syncthreads();
        for (int o = 128; o > 0; o >>= 1) {
            if (tid < o) sU[tid] += sU[tid + o];
            __syncthreads();
        }
        unsigned r = sU[0]; __syncthreads();
        return r;
    };

    unsigned cpos = count_gt(0.0f);  // negatives with strictly positive CE
    float negpart = 0.f;

    if ((unsigned long long)k <= (unsigned long long)cpos) {
        unsigned lo = 0u, hi = 0x7F800000u;
        while (hi - lo > 1u) {
            unsigned mid = lo + (hi - lo) / 2u;
            unsigned c = count_gt(__uint_as_float(mid));
            if (c >= (unsigned)k) lo = mid; else hi = mid;
        }
        float v = __uint_as_float(hi);  // the k-th largest value
        float ss = 0.f; unsigned c1 = 0;
        for (int an = tid; an < NANCH; an += 256) {
            size_t ba = (size_t)b * NANCH + an;
            int lbl = labels[ba];
            if (lbl > 0) continue;
            float con = con_from_row(cls_out + ba * NCLS, lbl);
            if (con > v) { ss += con; c1++; }
        }
        sF[tid] = ss; sU[tid] = c1; __syncthreads();
        for (int o = 128; o > 0; o >>= 1) {
            if (tid < o) { sF[tid] += sF[tid + o]; sU[tid] += sU[tid + o]; }
            __syncthreads();
        }
        if (tid == 0) { bcastF = sF[0] + (float)((unsigned)k - sU[0]) * v; }
        __syncthreads();
        negpart = bcastF;
    } else {
        if (tid == 0) {
            float np = 0.f;
            unsigned m = (unsigned)k - cpos;
            for (int an = 0; an < NANCH; ++an) {
                size_t ba = (size_t)b * NANCH + an;
                int lbl = labels[ba];
                float con = con_from_row(cls_out + ba * NCLS, lbl);
                float cneg = (lbl > 0) ? 0.f : con;
                if (cneg > 0.f) np += con;
                else if (m > 0u) { np += con; m--; }
            }
            bcastF = np;
        }
        __syncthreads();
        negpart = bcastF;
    }

    con_loss = a.sum_pos + negpart;
    if (tid == 0) {
        float denom = (a.cnt != 0u) ? (float)a.cnt : 1.f;
        atomicAdd(out, (a.loc + con_loss) / denom * (1.f / NBATCH));
    }
}

// ---------------------------------------------------------------- launch
extern "C" void kernel_launch(void* const* d_in, const int* in_sizes, int n_in,
                              void* d_out, int out_size, void* d_ws, size_t ws_size,
                              hipStream_t stream) {
    const float* loc_out = (const float*)d_in[0];
    const float* cls_out = (const float*)d_in[1];
    const float* loc_lab = (const float*)d_in[2];
    const int*   labels  = (const int*)d_in[3];
    float* out = (float*)d_out;
    BatchAcc* acc = (BatchAcc*)d_ws;   // 128*16 = 2 KB of ws

    init_kernel<<<1, 256, 0, stream>>>(acc, out);
    anchor_kernel<<<NBATCH * NCHUNK, K1_THREADS, 0, stream>>>(loc_out, cls_out, loc_lab, labels, acc);
    finalize_kernel<<<NBATCH, 256, 0, stream>>>(cls_out, labels, acc, out);
}